// Round 10
// baseline (22026.602 us; speedup 1.0000x reference)
//
#include <hip/hip_runtime.h>
#include <math.h>

#define B_  32
#define T_  512
#define I_  128
#define H_  512

// ---------------------------------------------------------------------------
// Tiled fp32 GEMM: C[m][n] = sum_k A[m][k] * Bm[n][k]  (+ bias[n] if bias)
// ---------------------------------------------------------------------------
__global__ __launch_bounds__(256) void gemm_abt(
    const float* __restrict__ A, const float* __restrict__ Bm, float* __restrict__ C,
    const float* __restrict__ bias, long sA, long sB, long sC, int ldc)
{
  __shared__ float Al[64][65];
  __shared__ float Bl[64][65];
  const long z = blockIdx.z;
  A += z * sA; Bm += z * sB; C += z * sC;
  const int m0 = blockIdx.x * 64, n0 = blockIdx.y * 64;
  const int tid = threadIdx.x;
  const int tx = tid & 15, ty = tid >> 4;
  float acc[4][4] = {};

  for (int h = 0; h < 2; ++h) {
    const int k0 = h * 64;
    __syncthreads();
    #pragma unroll
    for (int s = 0; s < 4; ++s) {
      int idx = tid + s * 256;
      int m  = idx >> 4;
      int k4 = (idx & 15) << 2;
      float4 a4 = *(const float4*)&A[(long)(m0 + m) * 128 + k0 + k4];
      Al[k4 + 0][m] = a4.x; Al[k4 + 1][m] = a4.y; Al[k4 + 2][m] = a4.z; Al[k4 + 3][m] = a4.w;
      float4 b4 = *(const float4*)&Bm[(long)(n0 + m) * 128 + k0 + k4];
      Bl[k4 + 0][m] = b4.x; Bl[k4 + 1][m] = b4.y; Bl[k4 + 2][m] = b4.z; Bl[k4 + 3][m] = b4.w;
    }
    __syncthreads();
    #pragma unroll 8
    for (int k = 0; k < 64; ++k) {
      float a0 = Al[k][ty*4+0], a1 = Al[k][ty*4+1], a2 = Al[k][ty*4+2], a3 = Al[k][ty*4+3];
      float b0 = Bl[k][tx*4+0], b1 = Bl[k][tx*4+1], b2 = Bl[k][tx*4+2], b3 = Bl[k][tx*4+3];
      acc[0][0] += a0*b0; acc[0][1] += a0*b1; acc[0][2] += a0*b2; acc[0][3] += a0*b3;
      acc[1][0] += a1*b0; acc[1][1] += a1*b1; acc[1][2] += a1*b2; acc[1][3] += a1*b3;
      acc[2][0] += a2*b0; acc[2][1] += a2*b1; acc[2][2] += a2*b2; acc[2][3] += a2*b3;
      acc[3][0] += a3*b0; acc[3][1] += a3*b1; acc[3][2] += a3*b2; acc[3][3] += a3*b3;
    }
  }
  #pragma unroll
  for (int i = 0; i < 4; ++i) {
    #pragma unroll
    for (int j = 0; j < 4; ++j) {
      float bb = bias ? bias[n0 + tx*4 + j] : 0.f;
      C[(long)(m0 + ty*4 + i) * ldc + n0 + tx*4 + j] = acc[i][j] + bb;
    }
  }
}

// ---------------------------------------------------------------------------
__global__ __launch_bounds__(512) void cumsum_k(const float* __restrict__ Deltas,
                                                float* __restrict__ dcum)
{
  __shared__ float s[512];
  const int b = blockIdx.x, t = threadIdx.x;
  s[t] = Deltas[b * 512 + t];
  __syncthreads();
  for (int off = 1; off < 512; off <<= 1) {
    float v = (t >= off) ? s[t - off] : 0.f;
    __syncthreads();
    s[t] += v;
    __syncthreads();
  }
  dcum[b * 512 + t] = s[t];
}

// ---------------------------------------------------------------------------
__global__ __launch_bounds__(64) void softmax_k(float* __restrict__ a,
                                                const float* __restrict__ dcum)
{
  const int t = blockIdx.x, b = blockIdx.y;
  float* row = a + ((long)b * T_ + t) * T_;
  const int lane = threadIdx.x;
  if (t == 0) {
    #pragma unroll
    for (int i = 0; i < 8; ++i) row[i * 64 + lane] = 0.f;
    return;
  }
  float vals[8];
  float mx = -3.4e38f;
  #pragma unroll
  for (int i = 0; i < 8; ++i) {
    int j = i * 64 + lane;
    float v = (j < t) ? row[j] : -3.4e38f;
    vals[i] = v; mx = fmaxf(mx, v);
  }
  #pragma unroll
  for (int off = 1; off < 64; off <<= 1) mx = fmaxf(mx, __shfl_xor(mx, off));
  float sum = 0.f;
  #pragma unroll
  for (int i = 0; i < 8; ++i) {
    int j = i * 64 + lane;
    float e = (j < t) ? expf(vals[i] - mx) : 0.f;
    vals[i] = e; sum += e;
  }
  #pragma unroll
  for (int off = 1; off < 64; off <<= 1) sum += __shfl_xor(sum, off);
  const float E = 2.718281828459045f;
  const float dct = dcum[b * 512 + t];
  const float inv = 1.f / sum;
  #pragma unroll
  for (int i = 0; i < 8; ++i) {
    int j = i * 64 + lane;
    float w = (j < t) ? 1.f / logf(E + dct - dcum[b * 512 + j]) : 0.f;
    row[j] = vals[i] * inv * w;
  }
}

// ---------------------------------------------------------------------------
// Agent-scope primitives (coherence-point traffic, no RMW anywhere).
// ---------------------------------------------------------------------------
__device__ __forceinline__ void st_wt(float* p, float v) {
  __hip_atomic_store(p, v, __ATOMIC_RELAXED, __HIP_MEMORY_SCOPE_AGENT);
}
__device__ __forceinline__ float ld_wt(const float* p) {
  return __hip_atomic_load(p, __ATOMIC_RELAXED, __HIP_MEMORY_SCOPE_AGENT);
}
__device__ __forceinline__ void stflag(unsigned* p, unsigned v) {
  __hip_atomic_store(p, v, __ATOMIC_RELAXED, __HIP_MEMORY_SCOPE_AGENT);
}
__device__ __forceinline__ unsigned ldflag(const unsigned* p) {
  return __hip_atomic_load(p, __ATOMIC_RELAXED, __HIP_MEMORY_SCOPE_AGENT);
}

// ---------------------------------------------------------------------------
// Persistent recurrent kernel. 256 blocks (32 batches x 8 h-slices) x 512
// threads, 1 block/CU. Block (b,hs) owns gate rows {q*512 + hs*64 + j} for
// q=0..3, j=0..63 and the U-update for its 64 h-columns: gates never leave
// the block. The ONLY cross-block dependency is the h-vector exchange among
// the 8 slice-blocks of batch b -> ONE sync hop per step, group of 8.
// W is register-stationary: thread (r=tid>>1, c2=tid&1) holds 320 fp32 of
// row r's [W_hh | W_ih] cols; x=[h(512)|v(128)] staged in LDS, wave reads
// are 2-address broadcasts (conflict-free). C = alpha.cn partials are
// computed BEFORE the h-wait (history-only), hiding work under the hop.
// ---------------------------------------------------------------------------
__global__ __launch_bounds__(512, 2) void recurrent_k(
    const float* __restrict__ v_buf,   // [B][T][I]
    const float* __restrict__ alpha,   // [B][T][T]
    const float* __restrict__ W_ih,    // [4H][I]
    const float* __restrict__ W_hh,    // [4H][H]
    const float* __restrict__ b_ih, const float* __restrict__ b_hh,
    float* out,                        // [B][T][H] = h_n (also h state)
    unsigned* bar)
{
  extern __shared__ float lds[];
  float* cn   = lds;                   // [512][64] cell history (block-local)
  float* xbuf = cn + 512 * 64;         // [640] = [h(512) | v(128)]
  float* gred = xbuf + 640;            // [256] gate values
  float* pc   = gred + 256;            // [512] C partials
  __shared__ int s_ab;

  const int tid = threadIdx.x;
  const int g = blockIdx.x;
  const int b = g >> 3, hs = g & 7;
  const int r = tid >> 1;                   // 0..255: gate-row local index
  const int q = r >> 6, j = r & 63;         // gate type, h-col local
  const int c2 = tid & 1;                   // col half: [c2*320, c2*320+320)
  const int R = q * 512 + hs * 64 + j;      // global gate row
  const int tg = tid >> 6, jl = tid & 63;   // C-phase role

  unsigned* abrt = bar + 4096;              // flags: bar[g*16], 64B lines

  // ---- stationary weights: 80 float4 = 320 cols of row R ----
  float4 wr[80];
  if (c2 == 0) {
    #pragma unroll
    for (int k = 0; k < 80; ++k)
      wr[k] = *(const float4*)&W_hh[(long)R * H_ + k * 4];
  } else {
    #pragma unroll
    for (int k = 0; k < 48; ++k)
      wr[k] = *(const float4*)&W_hh[(long)R * H_ + 320 + k * 4];
    #pragma unroll
    for (int k = 48; k < 80; ++k)
      wr[k] = *(const float4*)&W_ih[(long)R * I_ + (k - 48) * 4];
  }
  const float bias = b_ih[R] + b_hh[R];

  for (int t = 0; t < T_; ++t) {
    // ---- C partials first: history-only, overlaps the h-wait hop ----
    {
      float partial = 0.f;
      const float* arow = alpha + ((long)b * T_ + t) * T_;
      for (int tp = tg; tp < t; tp += 8)
        partial += arow[tp] * cn[tp * 64 + jl];
      pc[tid] = partial;
    }

    // ---- wait: all 8 slice-blocks of batch b published h(t-1) ----
    if (t > 0) {
      if (tid < 64) {
        long spins = 0; int ab = 0;
        const unsigned* fp = bar + (long)(b * 8 + (tid & 7)) * 16;
        for (;;) {
          unsigned f = ldflag(fp);
          if (__all((int)(f >= (unsigned)t))) break;
          if (((++spins) & 63) == 0) {
            if (ldflag(abrt)) { ab = 1; break; }
            if (spins > 2000000L) {
              __hip_atomic_store(abrt, 1u, __ATOMIC_RELAXED, __HIP_MEMORY_SCOPE_AGENT);
              ab = 1; break;
            }
          }
          __builtin_amdgcn_s_sleep(1);
        }
        if (tid == 0) s_ab = ab;
      }
      __syncthreads();
      if (s_ab) return;
      // stage x: h(t-1) via agent loads (coherence point), v(t) cached
      xbuf[tid] = ld_wt(&out[((long)b * T_ + (t - 1)) * H_ + tid]);
      if (tid < 128) xbuf[512 + tid] = v_buf[((long)b * T_ + t) * I_ + tid];
    } else {
      xbuf[tid] = 0.f;
      if (tid < 128) xbuf[512 + tid] = v_buf[((long)b * T_) * I_ + tid];
    }
    __syncthreads();

    // ---- G: full dot for row R over this thread's 320 cols ----
    float acc = 0.f;
    const float4* xb = (const float4*)xbuf + c2 * 80;
    #pragma unroll
    for (int k = 0; k < 80; ++k) {
      float4 x = xb[k];
      acc += wr[k].x * x.x + wr[k].y * x.y + wr[k].z * x.z + wr[k].w * x.w;
    }
    acc += __shfl_xor(acc, 1);            // pair (c2=0,1) -> full 640-dot
    if (c2 == 0) gred[r] = acc + bias;
    __syncthreads();

    // ---- U: all-local finish for this block's 64 h-cols ----
    if (tid < 64) {
      float gi = gred[tid], gf = gred[64 + tid], gg = gred[128 + tid], go = gred[192 + tid];
      float C = pc[tid] + pc[64 + tid] + pc[128 + tid] + pc[192 + tid]
              + pc[256 + tid] + pc[320 + tid] + pc[384 + tid] + pc[448 + tid];
      float si = 1.f / (1.f + expf(-gi));
      float sf = 1.f / (1.f + expf(-gf));
      float so = 1.f / (1.f + expf(-go));
      float cnew = sf * C + si * tanhf(gg);
      float hnew = so * tanhf(cnew);
      cn[t * 64 + tid] = cnew;
      st_wt(&out[((long)b * T_ + t) * H_ + hs * 64 + tid], hnew);
    }
    __syncthreads();                      // drains h stores (vmcnt(0))
    if (tid == 0) stflag(&bar[(long)g * 16], (unsigned)(t + 1));
  }
}

// ---------------------------------------------------------------------------
extern "C" void kernel_launch(void* const* d_in, const int* in_sizes, int n_in,
                              void* d_out, int out_size, void* d_ws, size_t ws_size,
                              hipStream_t stream)
{
  const float* values  = (const float*)d_in[0];
  const float* Deltas  = (const float*)d_in[1];
  // d_in[2] = ys (unused by the reference computation)
  const float* W_ih    = (const float*)d_in[3];
  const float* W_hh    = (const float*)d_in[4];
  const float* b_ih    = (const float*)d_in[5];
  const float* b_hh    = (const float*)d_in[6];
  const float* atten_W = (const float*)d_in[7];
  const float* atten_b = (const float*)d_in[8];
  float* out = (float*)d_out;

  char* ws = (char*)d_ws;
  unsigned* bar = (unsigned*)ws;                       // 20 KB flag region
  float* v_buf  = (float*)(ws + 69632);                // 8 MB   [B][T][I]
  float* a_buf  = (float*)(ws + 69632 + 8388608);      // 32 MB  [B][T][T]
  float* dcum   = (float*)(ws + 69632 + 8388608 + 33554432);           // 64 KB

  hipMemsetAsync(bar, 0, 20480, stream);

  // v = values @ atten_W^T + atten_b   (M=B*T=16384, N=128, K=128)
  gemm_abt<<<dim3(256, 2, 1), 256, 0, stream>>>(values, atten_W, v_buf, atten_b,
                                                0, 0, 0, 128);
  cumsum_k<<<32, 512, 0, stream>>>(Deltas, dcum);
  // a[b,t,j] = v[b,t,:] . values[b,j,:]   (per-batch 512x512x128)
  gemm_abt<<<dim3(8, 8, 32), 256, 0, stream>>>(v_buf, values, a_buf, nullptr,
                                               512L * 128, 512L * 128, 512L * 512, 512);
  softmax_k<<<dim3(512, 32), 64, 0, stream>>>(a_buf, dcum);

  // LDS: cn 131072 + xbuf 2560 + gred 1024 + pc 2048 = 136704 B
  (void)hipFuncSetAttribute((const void*)recurrent_k,
                            hipFuncAttributeMaxDynamicSharedMemorySize, 136704);
  recurrent_k<<<256, 512, 136704, stream>>>(v_buf, a_buf, W_ih, W_hh, b_ih, b_hh,
                                            out, bar);
}